// Round 4
// baseline (179.553 us; speedup 1.0000x reference)
//
#include <hip/hip_runtime.h>

typedef float f4v __attribute__((ext_vector_type(4)));

constexpr int   NUM_CLASSES  = 10;
constexpr float LAMBDA_COORD = 5.0f;
constexpr float LAMBDA_NOOBJ = 0.5f;
constexpr int   BLOCK = 256;
// 5,191,680 float4 slots = 2028 blocks * 256 threads * 10 tiles exactly
constexpr int   NBLOCKS_MAX = 2028;
constexpr int   LCONF = 20;     // per-wave conf-scalar exchange array

#define WAITVM3()  asm volatile("s_waitcnt vmcnt(3)" ::: "memory")
#define WAITVM0()  asm volatile("s_waitcnt vmcnt(0)" ::: "memory")
#define WAITLGKM() asm volatile("s_waitcnt lgkmcnt(0)" ::: "memory")
#define SB()       __builtin_amdgcn_sched_barrier(0)

// Identical math sequence to the verified kernels -> bit-exact partials.
__device__ __forceinline__ void slot(const f4v p, const f4v t,
                                     const float t4a, const float t4b,
                                     unsigned j0,
                                     float& coord, float& conf, float& cls)
{
#pragma unroll
    for (int m = 0; m < 4; ++m) {
        unsigned j  = j0 + (unsigned)m;
        float d     = p[m] - t[m];
        float sq    = d * d;
        float t4    = (j >= 15u) ? t4b : t4a;
        float sqo   = (t4 > 0.f) ? sq : 0.f;
        coord += ((j - 4u) >= 11u) ? sqo : 0.f;
        cls   += ((j - 5u) <  10u) ? sqo : 0.f;
    }
    bool  hasConf = (j0 - 1u) < 4u;            // j0 in [1,4]
    float pc = (j0 == 4u) ? p[0]
             : (j0 == 3u) ? p[1]
             : (j0 == 2u) ? p[2]
             :              p[3];
    float e   = __expf(-pc);
    float sig = 1.f / (1.f + e);
    bool  obj = t4a > 0.f;
    float dsv = sig - t4a;
    float confv = obj ? dsv * dsv : LAMBDA_NOOBJ * sig * sig;
    conf += hasConf ? confv : 0.f;
}

// Stage tile TT: pred + tgt float4 -> regs, plus ONE wave-uniform boundary
// conf scalar. Exactly 3 wave-level VMEM ops (deterministic vmcnt).
#define STAGE(TT, PREG, TREG, BREG) do {                                   \
    unsigned kk_ = idx + (unsigned)(TT) * S;                               \
    PREG = __builtin_nontemporal_load((const f4v*)pred + kk_);             \
    TREG = *((const f4v*)tgtp + kk_);                                      \
    unsigned wb_  = 4u * (kk_ - lane);        /* wave's first float */     \
    unsigned cl_  = wb_ / 15u;                                             \
    unsigned wo_  = wb_ - cl_ * 15u;          /* woff in [0,14] */         \
    unsigned rB_  = (wo_ >= 5u) ? 0u : 17u;   /* the one missing cell */   \
    unsigned pos_ = wb_ - wo_ + rB_ * 15u + 4u;                            \
    if (pos_ >= fTot) pos_ = fTot - 1u;       /* generic-shape safety */   \
    BREG = tgtp[pos_];                        /* uniform addr, 1 line */   \
} while (0)

// Consume tile TT: owner lanes publish their cell's conf scalar, lane 0
// publishes the boundary one, everyone reads t4a/t4b, then the math.
#define CONSUME(TT, PREG, TREG, BREG) do {                                 \
    unsigned kk_ = idx + (unsigned)(TT) * S;                               \
    unsigned wb_ = 4u * (kk_ - lane);                                      \
    unsigned cl_ = wb_ / 15u;                                              \
    unsigned wo_ = wb_ - cl_ * 15u;                                        \
    unsigned rB_ = (wo_ >= 5u) ? 0u : 17u;                                 \
    unsigned x_  = wo_ + 4u * lane;           /* <= 266 */                 \
    unsigned q_  = (x_ * 2185u) >> 15;        /* floor(x/15), u24 mul */   \
    unsigned j0_ = x_ - q_ * 15u;             /* == (4*kk) % 15 */         \
    if (lane == 0u) Lc[wv][rB_] = BREG;                                    \
    if (j0_ - 1u < 4u) {                      /* this lane owns a conf */  \
        float cv_ = (j0_ == 4u) ? TREG[0] : (j0_ == 3u) ? TREG[1]          \
                  : (j0_ == 2u) ? TREG[2] : TREG[3];                       \
        Lc[wv][q_] = cv_;                                                  \
    }                                                                      \
    WAITLGKM(); SB();                         /* writes before reads */    \
    float a_ = Lc[wv][q_];                                                 \
    float b_ = Lc[wv][q_ + ((j0_ >= 12u) ? 1u : 0u)];                      \
    slot(PREG, TREG, a_, b_, j0_, coord, conf, cls);                       \
} while (0)

__global__ __launch_bounds__(BLOCK) void yolo_main(
    const float* __restrict__ pred,
    const float* __restrict__ tgtp,
    float* __restrict__ ws,
    unsigned n4, unsigned nblocks)
{
    __shared__ float Lc[4][LCONF];            // 320 B total

    const unsigned tid  = threadIdx.x;
    const unsigned lane = tid & 63u;
    const unsigned wv   = tid >> 6;
    const unsigned S    = nblocks * 256u;
    const unsigned idx  = blockIdx.x * 256u + tid;
    const unsigned NTu  = n4 / S;             // 10 for the graded shape
    const unsigned fTot = 4u * n4;

    float coord = 0.f, conf = 0.f, cls = 0.f;
    f4v pA = {0,0,0,0}, tA = {0,0,0,0}, pB = {0,0,0,0}, tB = {0,0,0,0};
    float bA = 0.f, bB = 0.f;

    if (NTu >= 2u) {
        STAGE(0, pA, tA, bA); SB();
        STAGE(1, pB, tB, bB); SB();
        unsigned T = 0;
        for (; T + 1u < NTu; T += 2u) {
            // ---- tile T (regs A) ----
            WAITVM3(); SB();                  // T done; T+1's 3 ops in flight
            f4v pu = pA, tu = tA; float bu = bA;
            if (T + 2u < NTu) { STAGE(T + 2u, pA, tA, bA); }
            SB();
            CONSUME(T, pu, tu, bu);           // math hides T+2's loads

            // ---- tile T+1 (regs B) ----
            if (T + 3u < NTu) { WAITVM3(); } else { WAITVM0(); }
            SB();
            f4v pv = pB, tv = tB; float bv = bB;
            if (T + 3u < NTu) { STAGE(T + 3u, pB, tB, bB); }
            SB();
            CONSUME(T + 1u, pv, tv, bv);
        }
        if (T < NTu) {                        // odd NTu leftover (in A)
            WAITVM0(); SB();
            CONSUME(T, pA, tA, bA);
        }
    } else if (NTu == 1u) {
        STAGE(0, pA, tA, bA); SB();
        WAITVM0(); SB();
        CONSUME(0, pA, tA, bA);
    }

    // ragged remainder (n4 % S != 0) — empty for the graded shape
    for (unsigned k = NTu * S + idx; k < n4; k += S) {
        f4v p = *((const f4v*)pred + k);
        f4v t = *((const f4v*)tgtp + k);
        unsigned base  = 4u * k;
        unsigned cell0 = base / 15u;
        unsigned c15   = cell0 * 15u;
        unsigned j0    = base - c15;
        float ta = tgtp[c15 + 4u];
        float tb = tgtp[(j0 >= 12u) ? c15 + 19u : c15 + 4u];
        slot(p, t, ta, tb, j0, coord, conf, cls);
    }

    // wave64 shuffle reduce (unchanged topology -> bit-identical)
#pragma unroll
    for (int off = 32; off > 0; off >>= 1) {
        coord += __shfl_down(coord, off);
        conf  += __shfl_down(conf,  off);
        cls   += __shfl_down(cls,   off);
    }

    __shared__ float s[3][4];
    if (lane == 0) { s[0][wv] = coord; s[1][wv] = conf; s[2][wv] = cls; }
    __syncthreads();

    if (tid == 0) {
        float c0 = s[0][0] + s[0][1] + s[0][2] + s[0][3];
        float c1 = s[1][0] + s[1][1] + s[1][2] + s[1][3];
        float c2 = s[2][0] + s[2][1] + s[2][2] + s[2][3];
        ws[blockIdx.x]               = c0;
        ws[nblocks + blockIdx.x]     = c1;
        ws[2 * nblocks + blockIdx.x] = c2;
    }
}

__global__ __launch_bounds__(BLOCK) void yolo_finalize(
    const float* __restrict__ ws, float* __restrict__ out, unsigned nblocks)
{
    float c0 = 0.f, c1 = 0.f, c2 = 0.f;
    for (unsigned i = threadIdx.x; i < nblocks; i += BLOCK) {
        c0 += ws[i];
        c1 += ws[nblocks + i];
        c2 += ws[2 * nblocks + i];
    }
#pragma unroll
    for (int off = 32; off > 0; off >>= 1) {
        c0 += __shfl_down(c0, off);
        c1 += __shfl_down(c1, off);
        c2 += __shfl_down(c2, off);
    }
    __shared__ float s[3][4];
    int wave = threadIdx.x >> 6, lane = threadIdx.x & 63;
    if (lane == 0) { s[0][wave] = c0; s[1][wave] = c1; s[2][wave] = c2; }
    __syncthreads();
    if (threadIdx.x == 0) {
        float coord = LAMBDA_COORD * (s[0][0] + s[0][1] + s[0][2] + s[0][3]);
        float conf  =                 s[1][0] + s[1][1] + s[1][2] + s[1][3];
        float cls   = (1.f / NUM_CLASSES) * (s[2][0] + s[2][1] + s[2][2] + s[2][3]);
        out[0] = coord + conf + cls;
        out[1] = coord;
        out[2] = conf;
        out[3] = cls;
    }
}

extern "C" void kernel_launch(void* const* d_in, const int* in_sizes, int n_in,
                              void* d_out, int out_size, void* d_ws, size_t ws_size,
                              hipStream_t stream) {
    const float* pred = (const float*)d_in[0];
    const float* tgt  = (const float*)d_in[1];
    float* out = (float*)d_out;
    float* ws  = (float*)d_ws;

    unsigned total = (unsigned)in_sizes[0];   // B*S*S*15 = 20,766,720 (div by 4)
    unsigned n4    = total / 4u;

    unsigned nblocks = NBLOCKS_MAX;
    size_t need = (size_t)nblocks * 3 * sizeof(float);
    if (need > ws_size) nblocks = (unsigned)(ws_size / (3 * sizeof(float)));

    yolo_main<<<nblocks, BLOCK, 0, stream>>>(pred, tgt, ws, n4, nblocks);
    yolo_finalize<<<1, BLOCK, 0, stream>>>(ws, out, nblocks);
}

// Round 5
// 170.137 us; speedup vs baseline: 1.0553x; 1.0553x over previous
//
#include <hip/hip_runtime.h>

typedef float f4v __attribute__((ext_vector_type(4)));

constexpr int   NUM_CLASSES  = 10;
constexpr float LAMBDA_COORD = 5.0f;
constexpr float LAMBDA_NOOBJ = 0.5f;
constexpr int   BLOCK = 256;
// 5,191,680 float4 slots = 2028 blocks * 256 threads * 10 tiles exactly
constexpr int   NBLOCKS_MAX = 2028;
constexpr int   LCONF = 20;     // per-wave conf-scalar exchange array

#define WAITVM3()  asm volatile("s_waitcnt vmcnt(3)" ::: "memory")
#define WAITVM0()  asm volatile("s_waitcnt vmcnt(0)" ::: "memory")
#define WAITLGKM() asm volatile("s_waitcnt lgkmcnt(0)" ::: "memory")
#define SB()       __builtin_amdgcn_sched_barrier(0)

// Identical math sequence to the verified kernels -> bit-exact partials.
__device__ __forceinline__ void slot(const f4v p, const f4v t,
                                     const float t4a, const float t4b,
                                     unsigned j0,
                                     float& coord, float& conf, float& cls)
{
#pragma unroll
    for (int m = 0; m < 4; ++m) {
        unsigned j  = j0 + (unsigned)m;
        float d     = p[m] - t[m];
        float sq    = d * d;
        float t4    = (j >= 15u) ? t4b : t4a;
        float sqo   = (t4 > 0.f) ? sq : 0.f;
        coord += ((j - 4u) >= 11u) ? sqo : 0.f;
        cls   += ((j - 5u) <  10u) ? sqo : 0.f;
    }
    bool  hasConf = (j0 - 1u) < 4u;            // j0 in [1,4]
    float pc = (j0 == 4u) ? p[0]
             : (j0 == 3u) ? p[1]
             : (j0 == 2u) ? p[2]
             :              p[3];
    float e   = __expf(-pc);
    float sig = 1.f / (1.f + e);
    bool  obj = t4a > 0.f;
    float dsv = sig - t4a;
    float confv = obj ? dsv * dsv : LAMBDA_NOOBJ * sig * sig;
    conf += hasConf ? confv : 0.f;
}

// Stage tile TT: pred + tgt float4 -> regs, plus ONE wave-uniform boundary
// conf scalar. ALL loads non-temporal (no L3 allocation -> no dirty-victim
// writeback collision with the harness restore). Exactly 3 wave-level VMEM ops.
#define STAGE(TT, PREG, TREG, BREG) do {                                   \
    unsigned kk_ = idx + (unsigned)(TT) * S;                               \
    PREG = __builtin_nontemporal_load((const f4v*)pred + kk_);             \
    TREG = __builtin_nontemporal_load((const f4v*)tgtp + kk_);             \
    unsigned wb_  = 4u * (kk_ - lane);        /* wave's first float */     \
    unsigned cl_  = wb_ / 15u;                                             \
    unsigned wo_  = wb_ - cl_ * 15u;          /* woff in [0,14] */         \
    unsigned rB_  = (wo_ >= 5u) ? 0u : 17u;   /* the one missing cell */   \
    unsigned pos_ = wb_ - wo_ + rB_ * 15u + 4u;                            \
    if (pos_ >= fTot) pos_ = fTot - 1u;       /* generic-shape safety */   \
    BREG = __builtin_nontemporal_load(tgtp + pos_);  /* uniform addr */    \
} while (0)

// Consume tile TT: owner lanes publish their cell's conf scalar, lane 0
// publishes the boundary one, everyone reads t4a/t4b, then the math.
#define CONSUME(TT, PREG, TREG, BREG) do {                                 \
    unsigned kk_ = idx + (unsigned)(TT) * S;                               \
    unsigned wb_ = 4u * (kk_ - lane);                                      \
    unsigned cl_ = wb_ / 15u;                                              \
    unsigned wo_ = wb_ - cl_ * 15u;                                        \
    unsigned rB_ = (wo_ >= 5u) ? 0u : 17u;                                 \
    unsigned x_  = wo_ + 4u * lane;           /* <= 266 */                 \
    unsigned q_  = (x_ * 2185u) >> 15;        /* floor(x/15), u24 mul */   \
    unsigned j0_ = x_ - q_ * 15u;             /* == (4*kk) % 15 */         \
    if (lane == 0u) Lc[wv][rB_] = BREG;                                    \
    if (j0_ - 1u < 4u) {                      /* this lane owns a conf */  \
        float cv_ = (j0_ == 4u) ? TREG[0] : (j0_ == 3u) ? TREG[1]          \
                  : (j0_ == 2u) ? TREG[2] : TREG[3];                       \
        Lc[wv][q_] = cv_;                                                  \
    }                                                                      \
    WAITLGKM(); SB();                         /* writes before reads */    \
    float a_ = Lc[wv][q_];                                                 \
    float b_ = Lc[wv][q_ + ((j0_ >= 12u) ? 1u : 0u)];                      \
    slot(PREG, TREG, a_, b_, j0_, coord, conf, cls);                       \
} while (0)

__global__ __launch_bounds__(BLOCK) void yolo_main(
    const float* __restrict__ pred,
    const float* __restrict__ tgtp,
    float* __restrict__ ws,
    unsigned n4, unsigned nblocks)
{
    __shared__ float Lc[4][LCONF];            // 320 B total

    const unsigned tid  = threadIdx.x;
    const unsigned lane = tid & 63u;
    const unsigned wv   = tid >> 6;
    const unsigned S    = nblocks * 256u;
    const unsigned idx  = blockIdx.x * 256u + tid;
    const unsigned NTu  = n4 / S;             // 10 for the graded shape
    const unsigned fTot = 4u * n4;

    float coord = 0.f, conf = 0.f, cls = 0.f;
    f4v pA = {0,0,0,0}, tA = {0,0,0,0}, pB = {0,0,0,0}, tB = {0,0,0,0};
    float bA = 0.f, bB = 0.f;

    if (NTu >= 2u) {
        STAGE(0, pA, tA, bA); SB();
        STAGE(1, pB, tB, bB); SB();
        unsigned T = 0;
        for (; T + 1u < NTu; T += 2u) {
            // ---- tile T (regs A) ----
            WAITVM3(); SB();                  // T done; T+1's 3 ops in flight
            f4v pu = pA, tu = tA; float bu = bA;
            if (T + 2u < NTu) { STAGE(T + 2u, pA, tA, bA); }
            SB();
            CONSUME(T, pu, tu, bu);           // math hides T+2's loads

            // ---- tile T+1 (regs B) ----
            if (T + 3u < NTu) { WAITVM3(); } else { WAITVM0(); }
            SB();
            f4v pv = pB, tv = tB; float bv = bB;
            if (T + 3u < NTu) { STAGE(T + 3u, pB, tB, bB); }
            SB();
            CONSUME(T + 1u, pv, tv, bv);
        }
        if (T < NTu) {                        // odd NTu leftover (in A)
            WAITVM0(); SB();
            CONSUME(T, pA, tA, bA);
        }
    } else if (NTu == 1u) {
        STAGE(0, pA, tA, bA); SB();
        WAITVM0(); SB();
        CONSUME(0, pA, tA, bA);
    }

    // ragged remainder (n4 % S != 0) — empty for the graded shape
    for (unsigned k = NTu * S + idx; k < n4; k += S) {
        f4v p = *((const f4v*)pred + k);
        f4v t = *((const f4v*)tgtp + k);
        unsigned base  = 4u * k;
        unsigned cell0 = base / 15u;
        unsigned c15   = cell0 * 15u;
        unsigned j0    = base - c15;
        float ta = tgtp[c15 + 4u];
        float tb = tgtp[(j0 >= 12u) ? c15 + 19u : c15 + 4u];
        slot(p, t, ta, tb, j0, coord, conf, cls);
    }

    // wave64 shuffle reduce (unchanged topology -> bit-identical)
#pragma unroll
    for (int off = 32; off > 0; off >>= 1) {
        coord += __shfl_down(coord, off);
        conf  += __shfl_down(conf,  off);
        cls   += __shfl_down(cls,   off);
    }

    __shared__ float s[3][4];
    if (lane == 0) { s[0][wv] = coord; s[1][wv] = conf; s[2][wv] = cls; }
    __syncthreads();

    if (tid == 0) {
        float c0 = s[0][0] + s[0][1] + s[0][2] + s[0][3];
        float c1 = s[1][0] + s[1][1] + s[1][2] + s[1][3];
        float c2 = s[2][0] + s[2][1] + s[2][2] + s[2][3];
        ws[blockIdx.x]               = c0;
        ws[nblocks + blockIdx.x]     = c1;
        ws[2 * nblocks + blockIdx.x] = c2;
    }
}

__global__ __launch_bounds__(BLOCK) void yolo_finalize(
    const float* __restrict__ ws, float* __restrict__ out, unsigned nblocks)
{
    float c0 = 0.f, c1 = 0.f, c2 = 0.f;
    for (unsigned i = threadIdx.x; i < nblocks; i += BLOCK) {
        c0 += ws[i];
        c1 += ws[nblocks + i];
        c2 += ws[2 * nblocks + i];
    }
#pragma unroll
    for (int off = 32; off > 0; off >>= 1) {
        c0 += __shfl_down(c0, off);
        c1 += __shfl_down(c1, off);
        c2 += __shfl_down(c2, off);
    }
    __shared__ float s[3][4];
    int wave = threadIdx.x >> 6, lane = threadIdx.x & 63;
    if (lane == 0) { s[0][wave] = c0; s[1][wave] = c1; s[2][wave] = c2; }
    __syncthreads();
    if (threadIdx.x == 0) {
        float coord = LAMBDA_COORD * (s[0][0] + s[0][1] + s[0][2] + s[0][3]);
        float conf  =                 s[1][0] + s[1][1] + s[1][2] + s[1][3];
        float cls   = (1.f / NUM_CLASSES) * (s[2][0] + s[2][1] + s[2][2] + s[2][3]);
        out[0] = coord + conf + cls;
        out[1] = coord;
        out[2] = conf;
        out[3] = cls;
    }
}

extern "C" void kernel_launch(void* const* d_in, const int* in_sizes, int n_in,
                              void* d_out, int out_size, void* d_ws, size_t ws_size,
                              hipStream_t stream) {
    const float* pred = (const float*)d_in[0];
    const float* tgt  = (const float*)d_in[1];
    float* out = (float*)d_out;
    float* ws  = (float*)d_ws;

    unsigned total = (unsigned)in_sizes[0];   // B*S*S*15 = 20,766,720 (div by 4)
    unsigned n4    = total / 4u;

    unsigned nblocks = NBLOCKS_MAX;
    size_t need = (size_t)nblocks * 3 * sizeof(float);
    if (need > ws_size) nblocks = (unsigned)(ws_size / (3 * sizeof(float)));

    yolo_main<<<nblocks, BLOCK, 0, stream>>>(pred, tgt, ws, n4, nblocks);
    yolo_finalize<<<1, BLOCK, 0, stream>>>(ws, out, nblocks);
}